// Round 7
// baseline (377.010 us; speedup 1.0000x reference)
//
#include <hip/hip_runtime.h>
#include <math.h>

#define NN 50000
#define NE 800000

typedef unsigned short ushort_t;
typedef __attribute__((ext_vector_type(8))) short bf16x8;
typedef __attribute__((ext_vector_type(4))) float f32x4;

__device__ inline unsigned short f2bf(float f) {
    unsigned int u = __float_as_uint(f);
    u = (u + 0x7fffu + ((u >> 16) & 1u)) >> 16;
    return (unsigned short)u;
}
__device__ inline unsigned int pack2bf(float lo, float hi) {
    return (unsigned int)f2bf(lo) | ((unsigned int)f2bf(hi) << 16);
}

// ---------------- prep0: zero deg + compact edge index to int32 ----------------
__global__ void prep0_kernel(const int* __restrict__ ei, int istride,
                             int* __restrict__ esrc32, int* __restrict__ edst32,
                             int* __restrict__ deg) {
    int i = blockIdx.x * blockDim.x + threadIdx.x;
    int s = gridDim.x * blockDim.x;
    for (int j = i; j < NN; j += s) deg[j] = 0;
    const int* eis = ei;
    const int* eid = ei + (size_t)NE * istride;
    for (int j = i; j < NE; j += s) {
        esrc32[j] = eis[(size_t)j * istride];
        edst32[j] = eid[(size_t)j * istride];
    }
}

// ---------------- CSR build ----------------
__global__ void hist_kernel(const int* __restrict__ edst, int* __restrict__ deg, int nE) {
    int i = blockIdx.x * blockDim.x + threadIdx.x;
    int s = gridDim.x * blockDim.x;
    for (; i < nE; i += s) atomicAdd(&deg[edst[i]], 1);
}

__global__ __launch_bounds__(256)
void scan_reduce(const int* __restrict__ deg, int* __restrict__ bsum, int n) {
    __shared__ int s[256];
    const int t = threadIdx.x;
    const int i = blockIdx.x * 256 + t;
    s[t] = (i < n) ? deg[i] : 0;
    __syncthreads();
#pragma unroll
    for (int off = 128; off > 0; off >>= 1) {
        if (t < off) s[t] += s[t + off];
        __syncthreads();
    }
    if (t == 0) bsum[blockIdx.x] = s[0];
}

__global__ __launch_bounds__(256)
void scan_tops(const int* __restrict__ bsum, int* __restrict__ boff,
               int* __restrict__ rowptr, int nb, int n) {
    __shared__ int s[256];
    const int t = threadIdx.x;
    const int v = (t < nb) ? bsum[t] : 0;
    s[t] = v;
    __syncthreads();
    for (int off = 1; off < 256; off <<= 1) {
        int u = (t >= off) ? s[t - off] : 0;
        __syncthreads();
        s[t] += u;
        __syncthreads();
    }
    if (t < nb) boff[t] = s[t] - v;
    if (t == 255) rowptr[n] = s[255];
}

__global__ __launch_bounds__(256)
void scan_apply(int* __restrict__ deg, const int* __restrict__ boff,
                int* __restrict__ rowptr, int n) {
    __shared__ int s[256];
    const int t = threadIdx.x;
    const int i = blockIdx.x * 256 + t;
    const int v = (i < n) ? deg[i] : 0;
    s[t] = v;
    __syncthreads();
    for (int off = 1; off < 256; off <<= 1) {
        int u = (t >= off) ? s[t - off] : 0;
        __syncthreads();
        s[t] += u;
        __syncthreads();
    }
    if (i < n) {
        int ex = boff[blockIdx.x] + s[t] - v;
        rowptr[i] = ex;
        deg[i] = ex;
    }
}

__global__ void scatter_kernel(const int* __restrict__ esrc, const int* __restrict__ edst,
                               int* __restrict__ cursor, int* __restrict__ col, int nE) {
    int i = blockIdx.x * blockDim.x + threadIdx.x;
    int s = gridDim.x * blockDim.x;
    for (; i < nE; i += s) {
        int d = edst[i];
        int pos = atomicAdd(&cursor[d], 1);
        col[pos] = esrc[i];
    }
}

// ---------------- megaprep: all weight transforms + X pad + hacc zero ----------
__global__ void megaprep_kernel(const float* __restrict__ W1, const float* __restrict__ W2,
                                const float* __restrict__ W3, const float* __restrict__ Wf1,
                                const float* __restrict__ X,
                                ushort_t* __restrict__ Wt1, ushort_t* __restrict__ Wt2,
                                ushort_t* __restrict__ Wt3, ushort_t* __restrict__ Wf1t,
                                ushort_t* __restrict__ Xb, float* __restrict__ hacc) {
    const int T0 = 128 * 32;
    const int T1 = T0 + 256 * 64;
    const int T2 = T1 + 512 * 128;
    const int T3 = T2 + 256 * 256;
    const int T4 = T3 + NN * 32;
    const int T5 = T4 + NN;
    int i = blockIdx.x * blockDim.x + threadIdx.x;
    int s = gridDim.x * blockDim.x;
    for (; i < T5; i += s) {
        if (i < T0) {                       // Wt1[128][32], K-pad 16->32
            int idx = i, o = idx / 32, k = idx % 32;
            float v = 0.f;
            if (k < 16)
                v = (o < 64) ? (W1[k * 64 + o] - W1[(k + 16) * 64 + o])
                             : W1[(k + 16) * 64 + (o - 64)];
            Wt1[idx] = f2bf(v);
        } else if (i < T1) {                // Wt2[256][64], IN=64 OUT=128
            int idx = i - T0, o = idx / 64, k = idx % 64;
            float v = (o < 128) ? (W2[k * 128 + o] - W2[(k + 64) * 128 + o])
                                : W2[(k + 64) * 128 + (o - 128)];
            Wt2[idx] = f2bf(v);
        } else if (i < T2) {                // Wt3[512][128], IN=128 OUT=256
            int idx = i - T1, o = idx / 128, k = idx % 128;
            float v = (o < 256) ? (W3[(size_t)k * 256 + o] - W3[(size_t)(k + 128) * 256 + o])
                                : W3[(size_t)(k + 128) * 256 + (o - 256)];
            Wt3[idx] = f2bf(v);
        } else if (i < T3) {                // Wf1t[256][256] transpose
            int idx = i - T2, nn = idx / 256, k = idx % 256;
            Wf1t[idx] = f2bf(Wf1[(size_t)k * 256 + nn]);
        } else if (i < T4) {                // Xb[NN][32] bf16 zero-padded
            int idx = i - T3, row = idx >> 5, c = idx & 31;
            Xb[idx] = (c < 16) ? f2bf(X[(size_t)row * 16 + c]) : (ushort_t)0;
        } else {                            // hacc zero
            hacc[i - T4] = 0.f;
        }
    }
}

// ---------------- MFMA conv GEMM -> unified bf16 PQ table, bias folded -------
// PQ row layout: [bf16(P+bias) (OUT) | bf16(Q) (OUT)], NOUT=2*OUT
template<int K, int OUT, int NF, int MR>
__global__ __launch_bounds__(256)
void gemm_mfma(const ushort_t* __restrict__ A, const ushort_t* __restrict__ Wt,
               const float* __restrict__ bias, ushort_t* __restrict__ PQ, int n) {
    constexpr int NOUT = 2 * OUT;
    constexpr int KB = K / 32;
    const int wave = threadIdx.x >> 6;
    const int lane = threadIdx.x & 63;
    const int lr = lane & 15;
    const int kg = lane >> 4;
    const int row0 = (blockIdx.x * 4 + wave) * (MR * 16);
    const int col0 = blockIdx.y * (NF * 16);

    f32x4 acc[MR][NF];
#pragma unroll
    for (int m = 0; m < MR; ++m)
#pragma unroll
        for (int f = 0; f < NF; ++f) acc[m][f] = (f32x4)(0.f);

    const ushort_t* Ap[MR];
#pragma unroll
    for (int m = 0; m < MR; ++m) {
        int arow = row0 + m * 16 + lr;
        if (arow >= n) arow = n - 1;
        Ap[m] = A + (size_t)arow * K + kg * 8;
    }
    const ushort_t* Bp = Wt + (size_t)(col0 + lr) * K + kg * 8;

#pragma unroll
    for (int kb = 0; kb < KB; ++kb) {
        bf16x8 af[MR];
#pragma unroll
        for (int m = 0; m < MR; ++m) af[m] = *(const bf16x8*)(Ap[m] + kb * 32);
        bf16x8 bfv[NF];
#pragma unroll
        for (int f = 0; f < NF; ++f)
            bfv[f] = *(const bf16x8*)(Bp + (size_t)f * 16 * K + kb * 32);
#pragma unroll
        for (int f = 0; f < NF; ++f)
#pragma unroll
            for (int m = 0; m < MR; ++m)
                acc[m][f] = __builtin_amdgcn_mfma_f32_16x16x32_bf16(af[m], bfv[f], acc[m][f], 0, 0, 0);
    }

    // D layout: col = lr, row = kg*4 + r; P half gets bias
#pragma unroll
    for (int m = 0; m < MR; ++m) {
#pragma unroll
        for (int f = 0; f < NF; ++f) {
            int c = col0 + f * 16 + lr;
            float bb = (c < OUT) ? bias[c] : 0.f;
#pragma unroll
            for (int r = 0; r < 4; ++r) {
                int row = row0 + m * 16 + kg * 4 + r;
                if (row < n) PQ[(size_t)row * NOUT + c] = f2bf(acc[m][f][r] + bb);
            }
        }
    }
}

// ---------------- MFMA head: partial fc2 -> atomicAdd(hacc) ----------
__global__ __launch_bounds__(256)
void head_mfma(const ushort_t* __restrict__ H, const ushort_t* __restrict__ Wf1t,
               const float* __restrict__ bf1, const float* __restrict__ Wf2,
               float* __restrict__ hacc, int n) {
    const int wave = threadIdx.x >> 6;
    const int lane = threadIdx.x & 63;
    const int row0 = (blockIdx.x * 4 + wave) * 16;
    const int col0 = blockIdx.y * 128;
    const int lr = lane & 15;
    const int kg = lane >> 4;

    f32x4 acc[8];
#pragma unroll
    for (int i = 0; i < 8; ++i) acc[i] = (f32x4)(0.f);

    int arow = row0 + lr;
    if (arow >= n) arow = n - 1;
    const ushort_t* Aptr = H + (size_t)arow * 256 + kg * 8;
    const ushort_t* Bp = Wf1t + (size_t)(col0 + lr) * 256 + kg * 8;

#pragma unroll
    for (int kb = 0; kb < 8; ++kb) {
        bf16x8 afrag = *(const bf16x8*)(Aptr + kb * 32);
        bf16x8 bfv[8];
#pragma unroll
        for (int nf = 0; nf < 8; ++nf)
            bfv[nf] = *(const bf16x8*)(Bp + (size_t)nf * 16 * 256 + kb * 32);
#pragma unroll
        for (int nf = 0; nf < 8; ++nf)
            acc[nf] = __builtin_amdgcn_mfma_f32_16x16x32_bf16(afrag, bfv[nf], acc[nf], 0, 0, 0);
    }

    float part[4] = {0.f, 0.f, 0.f, 0.f};
#pragma unroll
    for (int nf = 0; nf < 8; ++nf) {
        int c = col0 + nf * 16 + lr;
        float w2 = Wf2[c];
        float bb = bf1[c];
#pragma unroll
        for (int r = 0; r < 4; ++r)
            part[r] = fmaf(fmaxf(acc[nf][r] + bb, 0.f), w2, part[r]);
    }
#pragma unroll
    for (int s = 1; s < 16; s <<= 1) {
#pragma unroll
        for (int r = 0; r < 4; ++r) part[r] += __shfl_xor(part[r], s, 16);
    }
    if (lr == 0) {
#pragma unroll
        for (int r = 0; r < 4; ++r) {
            int row = row0 + kg * 4 + r;
            if (row < n) atomicAdd(&hacc[row], part[r]);
        }
    }
}

__global__ void sigmoid_kernel(const float* __restrict__ hacc, const float* __restrict__ bf2,
                               float* __restrict__ out, int n) {
    int i = blockIdx.x * blockDim.x + threadIdx.x;
    int s = gridDim.x * blockDim.x;
    float b = bf2[0];
    for (; i < n; i += s) out[i] = 1.f / (1.f + expf(-(hacc[i] + b)));
}

// ---------------- segment-max over Q (bf16) + combine -> H bf16 ----------------
// PQ row: [Pb (OUT bf16) | Q (OUT bf16)];  H[i] = relu(Pb[i] + max_j Q[j])
template<int OUT>
__global__ __launch_bounds__(256, 8)
void segmax_combine(const ushort_t* __restrict__ PQ, const int* __restrict__ rowptr,
                    const int* __restrict__ col, ushort_t* __restrict__ Hout, int n) {
    constexpr int NOUT = 2 * OUT;
    constexpr int G = OUT / 8;
    constexpr int NPB = 256 / G;
    const int gid = threadIdx.x / G;
    const int lane = threadIdx.x % G;
    const int i = blockIdx.x * NPB + gid;
    if (i >= n) return;

    const int r0 = rowptr[i];
    const int r1 = rowptr[i + 1];
    const int c8 = lane * 8;

    float m[8];
#pragma unroll
    for (int j = 0; j < 8; ++j) m[j] = -INFINITY;

    auto domax = [&](uint4 q) {
        m[0] = fmaxf(m[0], __uint_as_float(q.x << 16));
        m[1] = fmaxf(m[1], __uint_as_float(q.x & 0xffff0000u));
        m[2] = fmaxf(m[2], __uint_as_float(q.y << 16));
        m[3] = fmaxf(m[3], __uint_as_float(q.y & 0xffff0000u));
        m[4] = fmaxf(m[4], __uint_as_float(q.z << 16));
        m[5] = fmaxf(m[5], __uint_as_float(q.z & 0xffff0000u));
        m[6] = fmaxf(m[6], __uint_as_float(q.w << 16));
        m[7] = fmaxf(m[7], __uint_as_float(q.w & 0xffff0000u));
    };

    int r = r0;
    for (; r + 3 < r1; r += 4) {
        int s0 = col[r], s1 = col[r + 1], s2 = col[r + 2], s3 = col[r + 3];
        uint4 q0 = *(const uint4*)(PQ + (size_t)s0 * NOUT + OUT + c8);
        uint4 q1 = *(const uint4*)(PQ + (size_t)s1 * NOUT + OUT + c8);
        uint4 q2 = *(const uint4*)(PQ + (size_t)s2 * NOUT + OUT + c8);
        uint4 q3 = *(const uint4*)(PQ + (size_t)s3 * NOUT + OUT + c8);
        domax(q0); domax(q1); domax(q2); domax(q3);
    }
    for (; r < r1; ++r) {
        domax(*(const uint4*)(PQ + (size_t)col[r] * NOUT + OUT + c8));
    }

    const uint4 pb = *(const uint4*)(PQ + (size_t)i * NOUT + c8);
    float p[8];
    p[0] = __uint_as_float(pb.x << 16); p[1] = __uint_as_float(pb.x & 0xffff0000u);
    p[2] = __uint_as_float(pb.y << 16); p[3] = __uint_as_float(pb.y & 0xffff0000u);
    p[4] = __uint_as_float(pb.z << 16); p[5] = __uint_as_float(pb.z & 0xffff0000u);
    p[6] = __uint_as_float(pb.w << 16); p[7] = __uint_as_float(pb.w & 0xffff0000u);

    float h[8];
#pragma unroll
    for (int j = 0; j < 8; ++j) h[j] = fmaxf(p[j] + m[j], 0.f);

    uint4 o;
    o.x = pack2bf(h[0], h[1]);
    o.y = pack2bf(h[2], h[3]);
    o.z = pack2bf(h[4], h[5]);
    o.w = pack2bf(h[6], h[7]);
    *(uint4*)(Hout + (size_t)i * OUT + c8) = o;
}

// ---------------- launch ----------------
extern "C" void kernel_launch(void* const* d_in, const int* in_sizes, int n_in,
                              void* d_out, int out_size, void* d_ws, size_t ws_size,
                              hipStream_t stream) {
    const float* X   = (const float*)d_in[0];
    const int*   ei  = (const int*)d_in[1];
    const float* W1  = (const float*)d_in[2];
    const float* b1  = (const float*)d_in[3];
    const float* W2  = (const float*)d_in[4];
    const float* b2  = (const float*)d_in[5];
    const float* W3  = (const float*)d_in[6];
    const float* b3  = (const float*)d_in[7];
    const float* Wf1 = (const float*)d_in[8];
    const float* bf1 = (const float*)d_in[9];
    const float* Wf2 = (const float*)d_in[10];
    const float* bf2 = (const float*)d_in[11];
    float* out = (float*)d_out;

    int istride = (in_sizes[1] == 4 * NE) ? 2 : 1;

    // workspace layout (16B-aligned segments)
    ushort_t* PQ     = (ushort_t*)d_ws;                 // NN*512 bf16 (51.2 MB)
    ushort_t* Ha     = PQ + (size_t)NN * 512;           // NN*256 bf16
    ushort_t* Hb     = Ha + (size_t)NN * 256;           // NN*256 bf16
    int*      rowptr = (int*)(Hb + (size_t)NN * 256);   // NN+8
    int*      deg    = rowptr + (NN + 8);               // NN
    int*      col    = deg + NN;                        // NE
    int*      esrc32 = col + NE;                        // NE
    int*      edst32 = esrc32 + NE;                     // NE
    int*      bsum   = edst32 + NE;                     // 256
    int*      boff   = bsum + 256;                      // 256
    ushort_t* Wt1    = (ushort_t*)(boff + 256);         // 128*32
    ushort_t* Wt2    = Wt1 + 128 * 32;                  // 256*64
    ushort_t* Wt3    = Wt2 + 256 * 64;                  // 512*128
    ushort_t* Wf1t   = Wt3 + 512 * 128;                 // 256*256
    ushort_t* Xb     = Wf1t + 256 * 256;                // NN*32
    float*    hacc   = (float*)(Xb + (size_t)NN * 32);  // NN

    const int NB = (NN + 255) / 256;

    // ---- edge compaction + CSR build ----
    prep0_kernel<<<1024, 256, 0, stream>>>(ei, istride, esrc32, edst32, deg);
    hist_kernel<<<1024, 256, 0, stream>>>(edst32, deg, NE);
    scan_reduce<<<NB, 256, 0, stream>>>(deg, bsum, NN);
    scan_tops<<<1, 256, 0, stream>>>(bsum, boff, rowptr, NB, NN);
    scan_apply<<<NB, 256, 0, stream>>>(deg, boff, rowptr, NN);
    scatter_kernel<<<1024, 256, 0, stream>>>(esrc32, edst32, deg, col, NE);

    // ---- weight / input prep (single kernel) ----
    megaprep_kernel<<<1024, 256, 0, stream>>>(W1, W2, W3, Wf1, X,
                                              Wt1, Wt2, Wt3, Wf1t, Xb, hacc);

    const int GB = (NN + 127) / 128;   // 128 rows/block

    // ---- layer 1: Xb[N,32] -> PQ[.,128] -> Ha bf16[.,64] ----
    {
        dim3 g(GB, 1);
        gemm_mfma<32, 64, 8, 2><<<g, 256, 0, stream>>>(Xb, Wt1, b1, PQ, NN);
    }
    segmax_combine<64><<<(NN + 31) / 32, 256, 0, stream>>>(PQ, rowptr, col, Ha, NN);

    // ---- layer 2: Ha -> PQ[.,256] -> Hb bf16[.,128] ----
    {
        dim3 g(GB, 2);
        gemm_mfma<64, 128, 8, 2><<<g, 256, 0, stream>>>(Ha, Wt2, b2, PQ, NN);
    }
    segmax_combine<128><<<(NN + 15) / 16, 256, 0, stream>>>(PQ, rowptr, col, Hb, NN);

    // ---- layer 3: Hb -> PQ[.,512] -> Ha bf16[.,256] ----
    {
        dim3 g(GB, 4);
        gemm_mfma<128, 256, 8, 2><<<g, 256, 0, stream>>>(Hb, Wt3, b3, PQ, NN);
    }
    segmax_combine<256><<<(NN + 7) / 8, 256, 0, stream>>>(PQ, rowptr, col, Ha, NN);

    // ---- MLP head: Ha -> hacc -> out ----
    {
        dim3 g((NN + 63) / 64, 2);
        head_mfma<<<g, 256, 0, stream>>>(Ha, Wf1t, bf1, Wf2, hacc, NN);
    }
    sigmoid_kernel<<<64, 256, 0, stream>>>(hacc, bf2, out, NN);
}

// Round 8
// 349.043 us; speedup vs baseline: 1.0801x; 1.0801x over previous
//
#include <hip/hip_runtime.h>
#include <math.h>

#define NN 50000
#define NE 800000

typedef unsigned short ushort_t;
typedef __attribute__((ext_vector_type(8))) short bf16x8;
typedef __attribute__((ext_vector_type(4))) float f32x4;

__device__ inline unsigned short f2bf(float f) {
    unsigned int u = __float_as_uint(f);
    u = (u + 0x7fffu + ((u >> 16) & 1u)) >> 16;
    return (unsigned short)u;
}
__device__ inline unsigned int pack2bf(float lo, float hi) {
    return (unsigned int)f2bf(lo) | ((unsigned int)f2bf(hi) << 16);
}

// ---------------- prep0: zero deg + compact edge index to int32 ----------------
__global__ void prep0_kernel(const int* __restrict__ ei, int istride,
                             int* __restrict__ esrc32, int* __restrict__ edst32,
                             int* __restrict__ deg) {
    int i = blockIdx.x * blockDim.x + threadIdx.x;
    int s = gridDim.x * blockDim.x;
    for (int j = i; j < NN; j += s) deg[j] = 0;
    const int* eis = ei;
    const int* eid = ei + (size_t)NE * istride;
    for (int j = i; j < NE; j += s) {
        esrc32[j] = eis[(size_t)j * istride];
        edst32[j] = eid[(size_t)j * istride];
    }
}

// ---------------- CSR build ----------------
__global__ void hist_kernel(const int* __restrict__ edst, int* __restrict__ deg, int nE) {
    int i = blockIdx.x * blockDim.x + threadIdx.x;
    int s = gridDim.x * blockDim.x;
    for (; i < nE; i += s) atomicAdd(&deg[edst[i]], 1);
}

__global__ __launch_bounds__(256)
void scan_reduce(const int* __restrict__ deg, int* __restrict__ bsum, int n) {
    __shared__ int s[256];
    const int t = threadIdx.x;
    const int i = blockIdx.x * 256 + t;
    s[t] = (i < n) ? deg[i] : 0;
    __syncthreads();
#pragma unroll
    for (int off = 128; off > 0; off >>= 1) {
        if (t < off) s[t] += s[t + off];
        __syncthreads();
    }
    if (t == 0) bsum[blockIdx.x] = s[0];
}

__global__ __launch_bounds__(256)
void scan_tops(const int* __restrict__ bsum, int* __restrict__ boff,
               int* __restrict__ rowptr, int nb, int n) {
    __shared__ int s[256];
    const int t = threadIdx.x;
    const int v = (t < nb) ? bsum[t] : 0;
    s[t] = v;
    __syncthreads();
    for (int off = 1; off < 256; off <<= 1) {
        int u = (t >= off) ? s[t - off] : 0;
        __syncthreads();
        s[t] += u;
        __syncthreads();
    }
    if (t < nb) boff[t] = s[t] - v;
    if (t == 255) rowptr[n] = s[255];
}

__global__ __launch_bounds__(256)
void scan_apply(int* __restrict__ deg, const int* __restrict__ boff,
                int* __restrict__ rowptr, int n) {
    __shared__ int s[256];
    const int t = threadIdx.x;
    const int i = blockIdx.x * 256 + t;
    const int v = (i < n) ? deg[i] : 0;
    s[t] = v;
    __syncthreads();
    for (int off = 1; off < 256; off <<= 1) {
        int u = (t >= off) ? s[t - off] : 0;
        __syncthreads();
        s[t] += u;
        __syncthreads();
    }
    if (i < n) {
        int ex = boff[blockIdx.x] + s[t] - v;
        rowptr[i] = ex;
        deg[i] = ex;
    }
}

__global__ void scatter_kernel(const int* __restrict__ esrc, const int* __restrict__ edst,
                               int* __restrict__ cursor, int* __restrict__ col, int nE) {
    int i = blockIdx.x * blockDim.x + threadIdx.x;
    int s = gridDim.x * blockDim.x;
    for (; i < nE; i += s) {
        int d = edst[i];
        int pos = atomicAdd(&cursor[d], 1);
        col[pos] = esrc[i];
    }
}

// ---------------- megaprep: all weight transforms + X pad + hacc zero ----------
__global__ void megaprep_kernel(const float* __restrict__ W1, const float* __restrict__ W2,
                                const float* __restrict__ W3, const float* __restrict__ Wf1,
                                const float* __restrict__ X,
                                ushort_t* __restrict__ Wt1, ushort_t* __restrict__ Wt2,
                                ushort_t* __restrict__ Wt3, ushort_t* __restrict__ Wf1t,
                                ushort_t* __restrict__ Xb, float* __restrict__ hacc) {
    const int T0 = 128 * 32;
    const int T1 = T0 + 256 * 64;
    const int T2 = T1 + 512 * 128;
    const int T3 = T2 + 256 * 256;
    const int T4 = T3 + NN * 32;
    const int T5 = T4 + NN;
    int i = blockIdx.x * blockDim.x + threadIdx.x;
    int s = gridDim.x * blockDim.x;
    for (; i < T5; i += s) {
        if (i < T0) {                       // Wt1[128][32], K-pad 16->32
            int idx = i, o = idx / 32, k = idx % 32;
            float v = 0.f;
            if (k < 16)
                v = (o < 64) ? (W1[k * 64 + o] - W1[(k + 16) * 64 + o])
                             : W1[(k + 16) * 64 + (o - 64)];
            Wt1[idx] = f2bf(v);
        } else if (i < T1) {                // Wt2[256][64], IN=64 OUT=128
            int idx = i - T0, o = idx / 64, k = idx % 64;
            float v = (o < 128) ? (W2[k * 128 + o] - W2[(k + 64) * 128 + o])
                                : W2[(k + 64) * 128 + (o - 128)];
            Wt2[idx] = f2bf(v);
        } else if (i < T2) {                // Wt3[512][128], IN=128 OUT=256
            int idx = i - T1, o = idx / 128, k = idx % 128;
            float v = (o < 256) ? (W3[(size_t)k * 256 + o] - W3[(size_t)(k + 128) * 256 + o])
                                : W3[(size_t)(k + 128) * 256 + (o - 256)];
            Wt3[idx] = f2bf(v);
        } else if (i < T3) {                // Wf1t[256][256] transpose
            int idx = i - T2, nn = idx / 256, k = idx % 256;
            Wf1t[idx] = f2bf(Wf1[(size_t)k * 256 + nn]);
        } else if (i < T4) {                // Xb[NN][32] bf16 zero-padded
            int idx = i - T3, row = idx >> 5, c = idx & 31;
            Xb[idx] = (c < 16) ? f2bf(X[(size_t)row * 16 + c]) : (ushort_t)0;
        } else {                            // hacc zero
            hacc[i - T4] = 0.f;
        }
    }
}

// ---------------- MFMA conv GEMM -> unified bf16 PQ table, bias folded -------
// PQ row layout: [bf16(P+bias) (OUT) | bf16(Q) (OUT)], NOUT=2*OUT
// Double-buffered frag loads; LDS-staged epilogue for coalesced 16B stores.
// Block = 4 waves x 32 rows = 128 rows; cols: blockIdx.y * 128.
template<int K, int OUT, int NF, int MR>
__global__ __launch_bounds__(256, 3)
void gemm_mfma(const ushort_t* __restrict__ A, const ushort_t* __restrict__ Wt,
               const float* __restrict__ bias, ushort_t* __restrict__ PQ, int n) {
    constexpr int NOUT = 2 * OUT;
    constexpr int KB = K / 32;
    __shared__ ushort_t lds[128][132];   // +4 pad: conflict-free frag writes

    const int wave = threadIdx.x >> 6;
    const int lane = threadIdx.x & 63;
    const int lr = lane & 15;
    const int kg = lane >> 4;
    const int row0b = blockIdx.x * (4 * MR * 16);          // block row base
    const int row0 = row0b + wave * (MR * 16);             // wave row base
    const int col0 = blockIdx.y * (NF * 16);

    f32x4 acc[MR][NF];
#pragma unroll
    for (int m = 0; m < MR; ++m)
#pragma unroll
        for (int f = 0; f < NF; ++f) acc[m][f] = (f32x4)(0.f);

    const ushort_t* Ap[MR];
#pragma unroll
    for (int m = 0; m < MR; ++m) {
        int arow = row0 + m * 16 + lr;
        if (arow >= n) arow = n - 1;
        Ap[m] = A + (size_t)arow * K + kg * 8;
    }
    const ushort_t* Bp = Wt + (size_t)(col0 + lr) * K + kg * 8;

    // software-pipelined K loop (double-buffered fragments, static indices)
    bf16x8 af[2][MR];
    bf16x8 bfv[2][NF];
#pragma unroll
    for (int m = 0; m < MR; ++m) af[0][m] = *(const bf16x8*)(Ap[m]);
#pragma unroll
    for (int f = 0; f < NF; ++f) bfv[0][f] = *(const bf16x8*)(Bp + (size_t)f * 16 * K);

#pragma unroll
    for (int kb = 0; kb < KB; ++kb) {
        const int cur = kb & 1, nxt = cur ^ 1;
        if (kb + 1 < KB) {
#pragma unroll
            for (int m = 0; m < MR; ++m)
                af[nxt][m] = *(const bf16x8*)(Ap[m] + (kb + 1) * 32);
#pragma unroll
            for (int f = 0; f < NF; ++f)
                bfv[nxt][f] = *(const bf16x8*)(Bp + (size_t)f * 16 * K + (kb + 1) * 32);
        }
#pragma unroll
        for (int f = 0; f < NF; ++f)
#pragma unroll
            for (int m = 0; m < MR; ++m)
                acc[m][f] = __builtin_amdgcn_mfma_f32_16x16x32_bf16(af[cur][m], bfv[cur][f], acc[m][f], 0, 0, 0);
    }

    // epilogue: fragments -> LDS (bias folded), then coalesced copy-out
#pragma unroll
    for (int m = 0; m < MR; ++m) {
#pragma unroll
        for (int f = 0; f < NF; ++f) {
            int cg = col0 + f * 16 + lr;
            float bb = (cg < OUT) ? bias[cg] : 0.f;
#pragma unroll
            for (int r = 0; r < 4; ++r) {
                lds[wave * (MR * 16) + m * 16 + kg * 4 + r][f * 16 + lr] =
                    f2bf(acc[m][f][r] + bb);
            }
        }
    }
    __syncthreads();

    const int t = threadIdx.x;
#pragma unroll
    for (int it = 0; it < 8; ++it) {
        int j = it * 256 + t;        // uint4 index among 128*16
        int row = j >> 4;
        int q = j & 15;
        int grow = row0b + row;
        if (grow < n) {
            uint4 v = *(const uint4*)(&lds[row][q * 8]);
            *(uint4*)(PQ + (size_t)grow * NOUT + col0 + q * 8) = v;
        }
    }
}

// ---------------- MFMA head: partial fc2 -> atomicAdd(hacc) ----------
__global__ __launch_bounds__(256, 4)
void head_mfma(const ushort_t* __restrict__ H, const ushort_t* __restrict__ Wf1t,
               const float* __restrict__ bf1, const float* __restrict__ Wf2,
               float* __restrict__ hacc, int n) {
    const int wave = threadIdx.x >> 6;
    const int lane = threadIdx.x & 63;
    const int row0 = (blockIdx.x * 4 + wave) * 16;
    const int col0 = blockIdx.y * 128;
    const int lr = lane & 15;
    const int kg = lane >> 4;

    f32x4 acc[8];
#pragma unroll
    for (int i = 0; i < 8; ++i) acc[i] = (f32x4)(0.f);

    int arow = row0 + lr;
    if (arow >= n) arow = n - 1;
    const ushort_t* Aptr = H + (size_t)arow * 256 + kg * 8;
    const ushort_t* Bp = Wf1t + (size_t)(col0 + lr) * 256 + kg * 8;

    bf16x8 afb[2], bfb[2][8];
    afb[0] = *(const bf16x8*)(Aptr);
#pragma unroll
    for (int nf = 0; nf < 8; ++nf) bfb[0][nf] = *(const bf16x8*)(Bp + (size_t)nf * 16 * 256);

#pragma unroll
    for (int kb = 0; kb < 8; ++kb) {
        const int cur = kb & 1, nxt = cur ^ 1;
        if (kb + 1 < 8) {
            afb[nxt] = *(const bf16x8*)(Aptr + (kb + 1) * 32);
#pragma unroll
            for (int nf = 0; nf < 8; ++nf)
                bfb[nxt][nf] = *(const bf16x8*)(Bp + (size_t)nf * 16 * 256 + (kb + 1) * 32);
        }
#pragma unroll
        for (int nf = 0; nf < 8; ++nf)
            acc[nf] = __builtin_amdgcn_mfma_f32_16x16x32_bf16(afb[cur], bfb[cur][nf], acc[nf], 0, 0, 0);
    }

    float part[4] = {0.f, 0.f, 0.f, 0.f};
#pragma unroll
    for (int nf = 0; nf < 8; ++nf) {
        int c = col0 + nf * 16 + lr;
        float w2 = Wf2[c];
        float bb = bf1[c];
#pragma unroll
        for (int r = 0; r < 4; ++r)
            part[r] = fmaf(fmaxf(acc[nf][r] + bb, 0.f), w2, part[r]);
    }
#pragma unroll
    for (int s = 1; s < 16; s <<= 1) {
#pragma unroll
        for (int r = 0; r < 4; ++r) part[r] += __shfl_xor(part[r], s, 16);
    }
    if (lr == 0) {
#pragma unroll
        for (int r = 0; r < 4; ++r) {
            int row = row0 + kg * 4 + r;
            if (row < n) atomicAdd(&hacc[row], part[r]);
        }
    }
}

__global__ void sigmoid_kernel(const float* __restrict__ hacc, const float* __restrict__ bf2,
                               float* __restrict__ out, int n) {
    int i = blockIdx.x * blockDim.x + threadIdx.x;
    int s = gridDim.x * blockDim.x;
    float b = bf2[0];
    for (; i < n; i += s) out[i] = 1.f / (1.f + expf(-(hacc[i] + b)));
}

// ---------------- segment-max over Q (bf16) + combine -> H bf16 ----------------
// PQ row: [Pb (OUT bf16) | Q (OUT bf16)];  H[i] = relu(Pb[i] + max_j Q[j])
template<int OUT>
__global__ __launch_bounds__(256, 8)
void segmax_combine(const ushort_t* __restrict__ PQ, const int* __restrict__ rowptr,
                    const int* __restrict__ col, ushort_t* __restrict__ Hout, int n) {
    constexpr int NOUT = 2 * OUT;
    constexpr int G = OUT / 8;
    constexpr int NPB = 256 / G;
    const int gid = threadIdx.x / G;
    const int lane = threadIdx.x % G;
    const int i = blockIdx.x * NPB + gid;
    if (i >= n) return;

    const int r0 = rowptr[i];
    const int r1 = rowptr[i + 1];
    const int c8 = lane * 8;

    float m[8];
#pragma unroll
    for (int j = 0; j < 8; ++j) m[j] = -INFINITY;

    auto domax = [&](uint4 q) {
        m[0] = fmaxf(m[0], __uint_as_float(q.x << 16));
        m[1] = fmaxf(m[1], __uint_as_float(q.x & 0xffff0000u));
        m[2] = fmaxf(m[2], __uint_as_float(q.y << 16));
        m[3] = fmaxf(m[3], __uint_as_float(q.y & 0xffff0000u));
        m[4] = fmaxf(m[4], __uint_as_float(q.z << 16));
        m[5] = fmaxf(m[5], __uint_as_float(q.z & 0xffff0000u));
        m[6] = fmaxf(m[6], __uint_as_float(q.w << 16));
        m[7] = fmaxf(m[7], __uint_as_float(q.w & 0xffff0000u));
    };

    int r = r0;
    for (; r + 3 < r1; r += 4) {
        int s0 = col[r], s1 = col[r + 1], s2 = col[r + 2], s3 = col[r + 3];
        uint4 q0 = *(const uint4*)(PQ + (size_t)s0 * NOUT + OUT + c8);
        uint4 q1 = *(const uint4*)(PQ + (size_t)s1 * NOUT + OUT + c8);
        uint4 q2 = *(const uint4*)(PQ + (size_t)s2 * NOUT + OUT + c8);
        uint4 q3 = *(const uint4*)(PQ + (size_t)s3 * NOUT + OUT + c8);
        domax(q0); domax(q1); domax(q2); domax(q3);
    }
    for (; r < r1; ++r) {
        domax(*(const uint4*)(PQ + (size_t)col[r] * NOUT + OUT + c8));
    }

    const uint4 pb = *(const uint4*)(PQ + (size_t)i * NOUT + c8);
    float p[8];
    p[0] = __uint_as_float(pb.x << 16); p[1] = __uint_as_float(pb.x & 0xffff0000u);
    p[2] = __uint_as_float(pb.y << 16); p[3] = __uint_as_float(pb.y & 0xffff0000u);
    p[4] = __uint_as_float(pb.z << 16); p[5] = __uint_as_float(pb.z & 0xffff0000u);
    p[6] = __uint_as_float(pb.w << 16); p[7] = __uint_as_float(pb.w & 0xffff0000u);

    float h[8];
#pragma unroll
    for (int j = 0; j < 8; ++j) h[j] = fmaxf(p[j] + m[j], 0.f);

    uint4 o;
    o.x = pack2bf(h[0], h[1]);
    o.y = pack2bf(h[2], h[3]);
    o.z = pack2bf(h[4], h[5]);
    o.w = pack2bf(h[6], h[7]);
    *(uint4*)(Hout + (size_t)i * OUT + c8) = o;
}

// ---------------- launch ----------------
extern "C" void kernel_launch(void* const* d_in, const int* in_sizes, int n_in,
                              void* d_out, int out_size, void* d_ws, size_t ws_size,
                              hipStream_t stream) {
    const float* X   = (const float*)d_in[0];
    const int*   ei  = (const int*)d_in[1];
    const float* W1  = (const float*)d_in[2];
    const float* b1  = (const float*)d_in[3];
    const float* W2  = (const float*)d_in[4];
    const float* b2  = (const float*)d_in[5];
    const float* W3  = (const float*)d_in[6];
    const float* b3  = (const float*)d_in[7];
    const float* Wf1 = (const float*)d_in[8];
    const float* bf1 = (const float*)d_in[9];
    const float* Wf2 = (const float*)d_in[10];
    const float* bf2 = (const float*)d_in[11];
    float* out = (float*)d_out;

    int istride = (in_sizes[1] == 4 * NE) ? 2 : 1;

    // workspace layout (16B-aligned segments)
    ushort_t* PQ     = (ushort_t*)d_ws;                 // NN*512 bf16 (51.2 MB)
    ushort_t* Ha     = PQ + (size_t)NN * 512;           // NN*256 bf16
    ushort_t* Hb     = Ha + (size_t)NN * 256;           // NN*256 bf16
    int*      rowptr = (int*)(Hb + (size_t)NN * 256);   // NN+8
    int*      deg    = rowptr + (NN + 8);               // NN
    int*      col    = deg + NN;                        // NE
    int*      esrc32 = col + NE;                        // NE
    int*      edst32 = esrc32 + NE;                     // NE
    int*      bsum   = edst32 + NE;                     // 256
    int*      boff   = bsum + 256;                      // 256
    ushort_t* Wt1    = (ushort_t*)(boff + 256);         // 128*32
    ushort_t* Wt2    = Wt1 + 128 * 32;                  // 256*64
    ushort_t* Wt3    = Wt2 + 256 * 64;                  // 512*128
    ushort_t* Wf1t   = Wt3 + 512 * 128;                 // 256*256
    ushort_t* Xb     = Wf1t + 256 * 256;                // NN*32
    float*    hacc   = (float*)(Xb + (size_t)NN * 32);  // NN

    const int NB = (NN + 255) / 256;

    // ---- edge compaction + CSR build ----
    prep0_kernel<<<1024, 256, 0, stream>>>(ei, istride, esrc32, edst32, deg);
    hist_kernel<<<1024, 256, 0, stream>>>(edst32, deg, NE);
    scan_reduce<<<NB, 256, 0, stream>>>(deg, bsum, NN);
    scan_tops<<<1, 256, 0, stream>>>(bsum, boff, rowptr, NB, NN);
    scan_apply<<<NB, 256, 0, stream>>>(deg, boff, rowptr, NN);
    scatter_kernel<<<1024, 256, 0, stream>>>(esrc32, edst32, deg, col, NE);

    // ---- weight / input prep (single kernel) ----
    megaprep_kernel<<<1024, 256, 0, stream>>>(W1, W2, W3, Wf1, X,
                                              Wt1, Wt2, Wt3, Wf1t, Xb, hacc);

    const int GB = (NN + 127) / 128;   // 128 rows/block

    // ---- layer 1: Xb[N,32] -> PQ[.,128] -> Ha bf16[.,64] ----
    {
        dim3 g(GB, 1);
        gemm_mfma<32, 64, 8, 2><<<g, 256, 0, stream>>>(Xb, Wt1, b1, PQ, NN);
    }
    segmax_combine<64><<<(NN + 31) / 32, 256, 0, stream>>>(PQ, rowptr, col, Ha, NN);

    // ---- layer 2: Ha -> PQ[.,256] -> Hb bf16[.,128] ----
    {
        dim3 g(GB, 2);
        gemm_mfma<64, 128, 8, 2><<<g, 256, 0, stream>>>(Ha, Wt2, b2, PQ, NN);
    }
    segmax_combine<128><<<(NN + 15) / 16, 256, 0, stream>>>(PQ, rowptr, col, Hb, NN);

    // ---- layer 3: Hb -> PQ[.,512] -> Ha bf16[.,256] ----
    {
        dim3 g(GB, 4);
        gemm_mfma<128, 256, 8, 2><<<g, 256, 0, stream>>>(Hb, Wt3, b3, PQ, NN);
    }
    segmax_combine<256><<<(NN + 7) / 8, 256, 0, stream>>>(PQ, rowptr, col, Ha, NN);

    // ---- MLP head: Ha -> hacc -> out ----
    {
        dim3 g((NN + 63) / 64, 2);
        head_mfma<<<g, 256, 0, stream>>>(Ha, Wf1t, bf1, Wf2, hacc, NN);
    }
    sigmoid_kernel<<<64, 256, 0, stream>>>(hacc, bf2, out, NN);
}

// Round 9
// 309.165 us; speedup vs baseline: 1.2194x; 1.1290x over previous
//
#include <hip/hip_runtime.h>
#include <math.h>

#define NN 50000
#define NE 800000

typedef unsigned short ushort_t;
typedef __attribute__((ext_vector_type(8))) short bf16x8;
typedef __attribute__((ext_vector_type(4))) float f32x4;

__device__ inline unsigned short f2bf(float f) {
    unsigned int u = __float_as_uint(f);
    u = (u + 0x7fffu + ((u >> 16) & 1u)) >> 16;
    return (unsigned short)u;
}
__device__ inline unsigned int pack2bf(float lo, float hi) {
    return (unsigned int)f2bf(lo) | ((unsigned int)f2bf(hi) << 16);
}

// ---------------- prep0: zero deg + compact edge index to int32 ----------------
__global__ void prep0_kernel(const int* __restrict__ ei, int istride,
                             int* __restrict__ esrc32, int* __restrict__ edst32,
                             int* __restrict__ deg) {
    int i = blockIdx.x * blockDim.x + threadIdx.x;
    int s = gridDim.x * blockDim.x;
    for (int j = i; j < NN; j += s) deg[j] = 0;
    const int* eis = ei;
    const int* eid = ei + (size_t)NE * istride;
    for (int j = i; j < NE; j += s) {
        esrc32[j] = eis[(size_t)j * istride];
        edst32[j] = eid[(size_t)j * istride];
    }
}

// ---------------- CSR build ----------------
__global__ void hist_kernel(const int* __restrict__ edst, int* __restrict__ deg, int nE) {
    int i = blockIdx.x * blockDim.x + threadIdx.x;
    int s = gridDim.x * blockDim.x;
    for (; i < nE; i += s) atomicAdd(&deg[edst[i]], 1);
}

__global__ __launch_bounds__(256)
void scan_reduce(const int* __restrict__ deg, int* __restrict__ bsum, int n) {
    __shared__ int s[256];
    const int t = threadIdx.x;
    const int i = blockIdx.x * 256 + t;
    s[t] = (i < n) ? deg[i] : 0;
    __syncthreads();
#pragma unroll
    for (int off = 128; off > 0; off >>= 1) {
        if (t < off) s[t] += s[t + off];
        __syncthreads();
    }
    if (t == 0) bsum[blockIdx.x] = s[0];
}

__global__ __launch_bounds__(256)
void scan_tops(const int* __restrict__ bsum, int* __restrict__ boff,
               int* __restrict__ rowptr, int nb, int n) {
    __shared__ int s[256];
    const int t = threadIdx.x;
    const int v = (t < nb) ? bsum[t] : 0;
    s[t] = v;
    __syncthreads();
    for (int off = 1; off < 256; off <<= 1) {
        int u = (t >= off) ? s[t - off] : 0;
        __syncthreads();
        s[t] += u;
        __syncthreads();
    }
    if (t < nb) boff[t] = s[t] - v;
    if (t == 255) rowptr[n] = s[255];
}

__global__ __launch_bounds__(256)
void scan_apply(int* __restrict__ deg, const int* __restrict__ boff,
                int* __restrict__ rowptr, int n) {
    __shared__ int s[256];
    const int t = threadIdx.x;
    const int i = blockIdx.x * 256 + t;
    const int v = (i < n) ? deg[i] : 0;
    s[t] = v;
    __syncthreads();
    for (int off = 1; off < 256; off <<= 1) {
        int u = (t >= off) ? s[t - off] : 0;
        __syncthreads();
        s[t] += u;
        __syncthreads();
    }
    if (i < n) {
        int ex = boff[blockIdx.x] + s[t] - v;
        rowptr[i] = ex;
        deg[i] = ex;
    }
}

__global__ void scatter_kernel(const int* __restrict__ esrc, const int* __restrict__ edst,
                               int* __restrict__ cursor, int* __restrict__ col, int nE) {
    int i = blockIdx.x * blockDim.x + threadIdx.x;
    int s = gridDim.x * blockDim.x;
    for (; i < nE; i += s) {
        int d = edst[i];
        int pos = atomicAdd(&cursor[d], 1);
        col[pos] = esrc[i];
    }
}

// ---------------- megaprep: all weight transforms + X pad + hacc zero ----------
__global__ void megaprep_kernel(const float* __restrict__ W1, const float* __restrict__ W2,
                                const float* __restrict__ W3, const float* __restrict__ Wf1,
                                const float* __restrict__ X,
                                ushort_t* __restrict__ Wt1, ushort_t* __restrict__ Wt2,
                                ushort_t* __restrict__ Wt3, ushort_t* __restrict__ Wf1t,
                                ushort_t* __restrict__ Xb, float* __restrict__ hacc) {
    const int T0 = 128 * 32;
    const int T1 = T0 + 256 * 64;
    const int T2 = T1 + 512 * 128;
    const int T3 = T2 + 256 * 256;
    const int T4 = T3 + NN * 32;
    const int T5 = T4 + NN;
    int i = blockIdx.x * blockDim.x + threadIdx.x;
    int s = gridDim.x * blockDim.x;
    for (; i < T5; i += s) {
        if (i < T0) {                       // Wt1[128][32], K-pad 16->32
            int idx = i, o = idx / 32, k = idx % 32;
            float v = 0.f;
            if (k < 16)
                v = (o < 64) ? (W1[k * 64 + o] - W1[(k + 16) * 64 + o])
                             : W1[(k + 16) * 64 + (o - 64)];
            Wt1[idx] = f2bf(v);
        } else if (i < T1) {                // Wt2[256][64], IN=64 OUT=128
            int idx = i - T0, o = idx / 64, k = idx % 64;
            float v = (o < 128) ? (W2[k * 128 + o] - W2[(k + 64) * 128 + o])
                                : W2[(k + 64) * 128 + (o - 128)];
            Wt2[idx] = f2bf(v);
        } else if (i < T2) {                // Wt3[512][128], IN=128 OUT=256
            int idx = i - T1, o = idx / 128, k = idx % 128;
            float v = (o < 256) ? (W3[(size_t)k * 256 + o] - W3[(size_t)(k + 128) * 256 + o])
                                : W3[(size_t)(k + 128) * 256 + (o - 256)];
            Wt3[idx] = f2bf(v);
        } else if (i < T3) {                // Wf1t[256][256] transpose
            int idx = i - T2, nn = idx / 256, k = idx % 256;
            Wf1t[idx] = f2bf(Wf1[(size_t)k * 256 + nn]);
        } else if (i < T4) {                // Xb[NN][32] bf16 zero-padded
            int idx = i - T3, row = idx >> 5, c = idx & 31;
            Xb[idx] = (c < 16) ? f2bf(X[(size_t)row * 16 + c]) : (ushort_t)0;
        } else {                            // hacc zero
            hacc[i - T4] = 0.f;
        }
    }
}

// ---------------- MFMA conv GEMM -> unified bf16 PQ table, bias folded -------
// PQ row layout: [bf16(P+bias) (OUT) | bf16(Q) (OUT)], NOUT=2*OUT
// Double-buffered frag loads; LDS-staged epilogue for coalesced 16B stores.
template<int K, int OUT, int NF, int MR>
__global__ __launch_bounds__(256, 3)
void gemm_mfma(const ushort_t* __restrict__ A, const ushort_t* __restrict__ Wt,
               const float* __restrict__ bias, ushort_t* __restrict__ PQ, int n) {
    constexpr int NOUT = 2 * OUT;
    constexpr int KB = K / 32;
    __shared__ ushort_t lds[128][132];   // +4 pad: conflict-free frag writes

    const int wave = threadIdx.x >> 6;
    const int lane = threadIdx.x & 63;
    const int lr = lane & 15;
    const int kg = lane >> 4;
    const int row0b = blockIdx.x * (4 * MR * 16);          // block row base
    const int row0 = row0b + wave * (MR * 16);             // wave row base
    const int col0 = blockIdx.y * (NF * 16);

    f32x4 acc[MR][NF];
#pragma unroll
    for (int m = 0; m < MR; ++m)
#pragma unroll
        for (int f = 0; f < NF; ++f) acc[m][f] = (f32x4)(0.f);

    const ushort_t* Ap[MR];
#pragma unroll
    for (int m = 0; m < MR; ++m) {
        int arow = row0 + m * 16 + lr;
        if (arow >= n) arow = n - 1;
        Ap[m] = A + (size_t)arow * K + kg * 8;
    }
    const ushort_t* Bp = Wt + (size_t)(col0 + lr) * K + kg * 8;

    bf16x8 af[2][MR];
    bf16x8 bfv[2][NF];
#pragma unroll
    for (int m = 0; m < MR; ++m) af[0][m] = *(const bf16x8*)(Ap[m]);
#pragma unroll
    for (int f = 0; f < NF; ++f) bfv[0][f] = *(const bf16x8*)(Bp + (size_t)f * 16 * K);

#pragma unroll
    for (int kb = 0; kb < KB; ++kb) {
        const int cur = kb & 1, nxt = cur ^ 1;
        if (kb + 1 < KB) {
#pragma unroll
            for (int m = 0; m < MR; ++m)
                af[nxt][m] = *(const bf16x8*)(Ap[m] + (kb + 1) * 32);
#pragma unroll
            for (int f = 0; f < NF; ++f)
                bfv[nxt][f] = *(const bf16x8*)(Bp + (size_t)f * 16 * K + (kb + 1) * 32);
        }
#pragma unroll
        for (int f = 0; f < NF; ++f)
#pragma unroll
            for (int m = 0; m < MR; ++m)
                acc[m][f] = __builtin_amdgcn_mfma_f32_16x16x32_bf16(af[cur][m], bfv[cur][f], acc[m][f], 0, 0, 0);
    }

    // epilogue: fragments -> LDS (bias folded), then coalesced copy-out
#pragma unroll
    for (int m = 0; m < MR; ++m) {
#pragma unroll
        for (int f = 0; f < NF; ++f) {
            int cg = col0 + f * 16 + lr;
            float bb = (cg < OUT) ? bias[cg] : 0.f;
#pragma unroll
            for (int r = 0; r < 4; ++r) {
                lds[wave * (MR * 16) + m * 16 + kg * 4 + r][f * 16 + lr] =
                    f2bf(acc[m][f][r] + bb);
            }
        }
    }
    __syncthreads();

    const int t = threadIdx.x;
#pragma unroll
    for (int it = 0; it < 8; ++it) {
        int j = it * 256 + t;        // uint4 index among 128*16
        int row = j >> 4;
        int q = j & 15;
        int grow = row0b + row;
        if (grow < n) {
            uint4 v = *(const uint4*)(&lds[row][q * 8]);
            *(uint4*)(PQ + (size_t)grow * NOUT + col0 + q * 8) = v;
        }
    }
}

// ---------------- MFMA head v3: LDS-shared B, MR=4, col-quarters ----------
// Block: 4 waves x 64 rows = 256 rows; grid (ceil(n/256), 4).
// Wf1t col-quarter [64 cols][256 K] staged in LDS (stride 264 -> 2-way free).
__global__ __launch_bounds__(256, 3)
void head_mfma(const ushort_t* __restrict__ H, const ushort_t* __restrict__ Wf1t,
               const float* __restrict__ bf1, const float* __restrict__ Wf2,
               float* __restrict__ hacc, int n) {
    __shared__ ushort_t ldsB[64 * 264];

    const int t = threadIdx.x;
    const int wave = t >> 6;
    const int lane = t & 63;
    const int lr = lane & 15;
    const int kg = lane >> 4;
    const int row0 = blockIdx.x * 256 + wave * 64;
    const int col0 = blockIdx.y * 64;

    // stage B: 64 rows x 256 K (bf16) -> LDS, 16B chunks
#pragma unroll
    for (int it = 0; it < 8; ++it) {
        int j = it * 256 + t;          // uint4 index among 64*32
        int row = j >> 5;
        int q = j & 31;
        uint4 v = *(const uint4*)(Wf1t + (size_t)(col0 + row) * 256 + q * 8);
        *(uint4*)(&ldsB[row * 264 + q * 8]) = v;
    }
    __syncthreads();

    f32x4 acc[4][4];
#pragma unroll
    for (int m = 0; m < 4; ++m)
#pragma unroll
        for (int f = 0; f < 4; ++f) acc[m][f] = (f32x4)(0.f);

    const ushort_t* Ap[4];
#pragma unroll
    for (int m = 0; m < 4; ++m) {
        int arow = row0 + m * 16 + lr;
        if (arow >= n) arow = n - 1;
        Ap[m] = H + (size_t)arow * 256 + kg * 8;
    }
    const ushort_t* Bl = ldsB + lr * 264 + kg * 8;

#pragma unroll
    for (int kb = 0; kb < 8; ++kb) {
        bf16x8 af[4];
#pragma unroll
        for (int m = 0; m < 4; ++m) af[m] = *(const bf16x8*)(Ap[m] + kb * 32);
        bf16x8 bfv[4];
#pragma unroll
        for (int f = 0; f < 4; ++f)
            bfv[f] = *(const bf16x8*)(Bl + f * 16 * 264 + kb * 32);
#pragma unroll
        for (int f = 0; f < 4; ++f)
#pragma unroll
            for (int m = 0; m < 4; ++m)
                acc[m][f] = __builtin_amdgcn_mfma_f32_16x16x32_bf16(af[m], bfv[f], acc[m][f], 0, 0, 0);
    }

    // partial fc2 over this col-quarter
    float part[4][4];
#pragma unroll
    for (int m = 0; m < 4; ++m)
#pragma unroll
        for (int r = 0; r < 4; ++r) part[m][r] = 0.f;

#pragma unroll
    for (int f = 0; f < 4; ++f) {
        int c = col0 + f * 16 + lr;
        float w2 = Wf2[c];
        float bb = bf1[c];
#pragma unroll
        for (int m = 0; m < 4; ++m)
#pragma unroll
            for (int r = 0; r < 4; ++r)
                part[m][r] = fmaf(fmaxf(acc[m][f][r] + bb, 0.f), w2, part[m][r]);
    }
#pragma unroll
    for (int s = 1; s < 16; s <<= 1) {
#pragma unroll
        for (int m = 0; m < 4; ++m)
#pragma unroll
            for (int r = 0; r < 4; ++r)
                part[m][r] += __shfl_xor(part[m][r], s, 16);
    }
    if (lr == 0) {
#pragma unroll
        for (int m = 0; m < 4; ++m)
#pragma unroll
            for (int r = 0; r < 4; ++r) {
                int row = row0 + m * 16 + kg * 4 + r;
                if (row < n) atomicAdd(&hacc[row], part[m][r]);
            }
    }
}

__global__ void sigmoid_kernel(const float* __restrict__ hacc, const float* __restrict__ bf2,
                               float* __restrict__ out, int n) {
    int i = blockIdx.x * blockDim.x + threadIdx.x;
    int s = gridDim.x * blockDim.x;
    float b = bf2[0];
    for (; i < n; i += s) out[i] = 1.f / (1.f + expf(-(hacc[i] + b)));
}

// ---------------- segment-max over Q (bf16) + combine -> H bf16 ----------------
template<int OUT>
__global__ __launch_bounds__(256, 8)
void segmax_combine(const ushort_t* __restrict__ PQ, const int* __restrict__ rowptr,
                    const int* __restrict__ col, ushort_t* __restrict__ Hout, int n) {
    constexpr int NOUT = 2 * OUT;
    constexpr int G = OUT / 8;
    constexpr int NPB = 256 / G;
    const int gid = threadIdx.x / G;
    const int lane = threadIdx.x % G;
    const int i = blockIdx.x * NPB + gid;
    if (i >= n) return;

    const int r0 = rowptr[i];
    const int r1 = rowptr[i + 1];
    const int c8 = lane * 8;

    float m[8];
#pragma unroll
    for (int j = 0; j < 8; ++j) m[j] = -INFINITY;

    auto domax = [&](uint4 q) {
        m[0] = fmaxf(m[0], __uint_as_float(q.x << 16));
        m[1] = fmaxf(m[1], __uint_as_float(q.x & 0xffff0000u));
        m[2] = fmaxf(m[2], __uint_as_float(q.y << 16));
        m[3] = fmaxf(m[3], __uint_as_float(q.y & 0xffff0000u));
        m[4] = fmaxf(m[4], __uint_as_float(q.z << 16));
        m[5] = fmaxf(m[5], __uint_as_float(q.z & 0xffff0000u));
        m[6] = fmaxf(m[6], __uint_as_float(q.w << 16));
        m[7] = fmaxf(m[7], __uint_as_float(q.w & 0xffff0000u));
    };

    int r = r0;
    for (; r + 3 < r1; r += 4) {
        int s0 = col[r], s1 = col[r + 1], s2 = col[r + 2], s3 = col[r + 3];
        uint4 q0 = *(const uint4*)(PQ + (size_t)s0 * NOUT + OUT + c8);
        uint4 q1 = *(const uint4*)(PQ + (size_t)s1 * NOUT + OUT + c8);
        uint4 q2 = *(const uint4*)(PQ + (size_t)s2 * NOUT + OUT + c8);
        uint4 q3 = *(const uint4*)(PQ + (size_t)s3 * NOUT + OUT + c8);
        domax(q0); domax(q1); domax(q2); domax(q3);
    }
    for (; r < r1; ++r) {
        domax(*(const uint4*)(PQ + (size_t)col[r] * NOUT + OUT + c8));
    }

    const uint4 pb = *(const uint4*)(PQ + (size_t)i * NOUT + c8);
    float p[8];
    p[0] = __uint_as_float(pb.x << 16); p[1] = __uint_as_float(pb.x & 0xffff0000u);
    p[2] = __uint_as_float(pb.y << 16); p[3] = __uint_as_float(pb.y & 0xffff0000u);
    p[4] = __uint_as_float(pb.z << 16); p[5] = __uint_as_float(pb.z & 0xffff0000u);
    p[6] = __uint_as_float(pb.w << 16); p[7] = __uint_as_float(pb.w & 0xffff0000u);

    float h[8];
#pragma unroll
    for (int j = 0; j < 8; ++j) h[j] = fmaxf(p[j] + m[j], 0.f);

    uint4 o;
    o.x = pack2bf(h[0], h[1]);
    o.y = pack2bf(h[2], h[3]);
    o.z = pack2bf(h[4], h[5]);
    o.w = pack2bf(h[6], h[7]);
    *(uint4*)(Hout + (size_t)i * OUT + c8) = o;
}

// ---------------- launch ----------------
extern "C" void kernel_launch(void* const* d_in, const int* in_sizes, int n_in,
                              void* d_out, int out_size, void* d_ws, size_t ws_size,
                              hipStream_t stream) {
    const float* X   = (const float*)d_in[0];
    const int*   ei  = (const int*)d_in[1];
    const float* W1  = (const float*)d_in[2];
    const float* b1  = (const float*)d_in[3];
    const float* W2  = (const float*)d_in[4];
    const float* b2  = (const float*)d_in[5];
    const float* W3  = (const float*)d_in[6];
    const float* b3  = (const float*)d_in[7];
    const float* Wf1 = (const float*)d_in[8];
    const float* bf1 = (const float*)d_in[9];
    const float* Wf2 = (const float*)d_in[10];
    const float* bf2 = (const float*)d_in[11];
    float* out = (float*)d_out;

    int istride = (in_sizes[1] == 4 * NE) ? 2 : 1;

    // workspace layout (16B-aligned segments)
    ushort_t* PQ     = (ushort_t*)d_ws;                 // NN*512 bf16 (51.2 MB)
    ushort_t* Ha     = PQ + (size_t)NN * 512;           // NN*256 bf16
    ushort_t* Hb     = Ha + (size_t)NN * 256;           // NN*256 bf16
    int*      rowptr = (int*)(Hb + (size_t)NN * 256);   // NN+8
    int*      deg    = rowptr + (NN + 8);               // NN
    int*      col    = deg + NN;                        // NE
    int*      esrc32 = col + NE;                        // NE
    int*      edst32 = esrc32 + NE;                     // NE
    int*      bsum   = edst32 + NE;                     // 256
    int*      boff   = bsum + 256;                      // 256
    ushort_t* Wt1    = (ushort_t*)(boff + 256);         // 128*32
    ushort_t* Wt2    = Wt1 + 128 * 32;                  // 256*64
    ushort_t* Wt3    = Wt2 + 256 * 64;                  // 512*128
    ushort_t* Wf1t   = Wt3 + 512 * 128;                 // 256*256
    ushort_t* Xb     = Wf1t + 256 * 256;                // NN*32
    float*    hacc   = (float*)(Xb + (size_t)NN * 32);  // NN

    const int NB = (NN + 255) / 256;

    // ---- edge compaction + CSR build ----
    prep0_kernel<<<1024, 256, 0, stream>>>(ei, istride, esrc32, edst32, deg);
    hist_kernel<<<1024, 256, 0, stream>>>(edst32, deg, NE);
    scan_reduce<<<NB, 256, 0, stream>>>(deg, bsum, NN);
    scan_tops<<<1, 256, 0, stream>>>(bsum, boff, rowptr, NB, NN);
    scan_apply<<<NB, 256, 0, stream>>>(deg, boff, rowptr, NN);
    scatter_kernel<<<1024, 256, 0, stream>>>(esrc32, edst32, deg, col, NE);

    // ---- weight / input prep (single kernel) ----
    megaprep_kernel<<<1024, 256, 0, stream>>>(W1, W2, W3, Wf1, X,
                                              Wt1, Wt2, Wt3, Wf1t, Xb, hacc);

    const int GB = (NN + 127) / 128;   // 128 rows/block

    // ---- layer 1: Xb[N,32] -> PQ[.,128] -> Ha bf16[.,64] ----
    {
        dim3 g(GB, 1);
        gemm_mfma<32, 64, 8, 2><<<g, 256, 0, stream>>>(Xb, Wt1, b1, PQ, NN);
    }
    segmax_combine<64><<<(NN + 31) / 32, 256, 0, stream>>>(PQ, rowptr, col, Ha, NN);

    // ---- layer 2: Ha -> PQ[.,256] -> Hb bf16[.,128] ----
    {
        dim3 g(GB, 2);
        gemm_mfma<64, 128, 8, 2><<<g, 256, 0, stream>>>(Ha, Wt2, b2, PQ, NN);
    }
    segmax_combine<128><<<(NN + 15) / 16, 256, 0, stream>>>(PQ, rowptr, col, Hb, NN);

    // ---- layer 3: Hb -> PQ[.,512] -> Ha bf16[.,256] ----
    {
        dim3 g(GB, 4);
        gemm_mfma<128, 256, 8, 2><<<g, 256, 0, stream>>>(Hb, Wt3, b3, PQ, NN);
    }
    segmax_combine<256><<<(NN + 7) / 8, 256, 0, stream>>>(PQ, rowptr, col, Ha, NN);

    // ---- MLP head: Ha -> hacc -> out ----
    {
        dim3 g((NN + 255) / 256, 4);
        head_mfma<<<g, 256, 0, stream>>>(Ha, Wf1t, bf1, Wf2, hacc, NN);
    }
    sigmoid_kernel<<<64, 256, 0, stream>>>(hacc, bf2, out, NN);
}